// Round 4
// baseline (236.212 us; speedup 1.0000x reference)
//
#include <hip/hip_runtime.h>

constexpr int kB  = 16;
constexpr int kLM = 1024;
constexpr int kLX = 1024;
constexpr int kD  = 768;

using short8 = __attribute__((ext_vector_type(8))) short;
using f32x4  = __attribute__((ext_vector_type(4))) float;

__device__ __forceinline__ unsigned short f2bf(float f) {
    unsigned u = __float_as_uint(f);
    u = (u + 0x7FFF + ((u >> 16) & 1)) >> 16;   // RNE
    return (unsigned short)u;
}
__device__ __forceinline__ float bf2f(unsigned short h) {
    return __uint_as_float(((unsigned)h) << 16);
}

// async 16B global->LDS copy; dst must be wave-uniform base + lane*16.
__device__ __forceinline__ void gl_lds16(const unsigned short* g, unsigned short* l) {
    auto gp = (const __attribute__((address_space(1))) unsigned int*)g;
    auto lp = (__attribute__((address_space(3))) unsigned int*)l;
    __builtin_amdgcn_global_load_lds(gp, lp, 16, 0, 0);
}

// cvt 8 fp32 -> one 16B bf16 chunk
__device__ __forceinline__ void writeChunk(unsigned short* dst, float4 lo, float4 hi) {
    union { short8 v; unsigned short u[8]; } o;
    o.u[0] = f2bf(lo.x); o.u[1] = f2bf(lo.y); o.u[2] = f2bf(lo.z); o.u[3] = f2bf(lo.w);
    o.u[4] = f2bf(hi.x); o.u[5] = f2bf(hi.y); o.u[6] = f2bf(hi.z); o.u[7] = f2bf(hi.w);
    *(short8*)dst = o.v;
}

// ---------------------------------------------------------------------------
// 256x256 8-phase bf16 MFMA GEMM core (m201-template port). BK=64, 512 thr
// (8 waves, 2M x 4N; per-wave output 128x64 = 8x4 16x16 frags).
// C[i][j] = sum_k A[i,k] B[j,k] (NT).
//
// LDS per operand per buffer: 256 rows x 8 chunks of 16B, XOR-swizzled:
// slot p holds global (row=p>>3, ch=(p&7)^(row&7)). Staging: thread t DMAs
// slots {t+512m} -> lane-linear LDS dest, contiguous full-128B-line global
// src. ds_read_b128 of frag (row, ch^row&7) is conflict-free (measured 0).
//
// Schedule per K-tile (4 phases, 2 barriers each):
//  ph0: [stage A-half0 of t+1] vmcnt(2) BAR | ds_read all B (8xb128) +
//       A m0-1 (4) | BAR? no: lgkm(0) schedbar prio1 16xMFMA prio0 BAR
//  ph1: ds_read A m2-3; [stage A-half1] BAR lgkm(0) 16xMFMA BAR
//  ph2: ds_read A m4-5; [stage B-half0] BAR lgkm(0) 16xMFMA BAR
//  ph3: ds_read A m6-7; [stage B-half1] BAR lgkm(0) 16xMFMA BAR
// vmcnt never drains to 0 in the main loop (gate = vmcnt(2), once/K-tile).
// Hazards: buf[(t+1)&1] writers ordered after iter t-1's final collective
// barrier (all waves' reads done); ds_read of buf[t&1] after vmcnt gate+BAR.
// sched_barrier(0) after each lgkmcnt(0) asm (rule #18: hipcc hoists MFMA
// past inline-asm waitcnt otherwise).
// ---------------------------------------------------------------------------
__device__ __forceinline__ void gemm_core256(
    const unsigned short* __restrict__ Ab, const unsigned short* __restrict__ Bb,
    unsigned short* __restrict__ Cb, unsigned short* __restrict__ Cm,
    int N, int K, unsigned short* As0, unsigned short* Bs0) {
    const int t    = threadIdx.x;
    const int wave = t >> 6, lane = t & 63;
    const int wm = wave >> 2, wn = wave & 3;          // 2 x 4 wave grid
    const int quad = lane >> 4, l15 = lane & 15;

    // staging: 4 slots per operand per thread (2 per half-tile)
    size_t goff[4];
    int    lof[4];
#pragma unroll
    for (int m = 0; m < 4; ++m) {
        const int p   = t + 512 * m;
        const int row = p >> 3;
        const int ch  = (p & 7) ^ (row & 7);
        goff[m] = (size_t)row * K + ch * 8;
        lof[m]  = p * 8;                              // LDS offset in shorts
    }

    // fragment read bases
    const int arow = wm * 128 + l15;                  // + m*16
    const int brow = wn * 64  + l15;                  // + n*16
    const int cx0  = quad ^ (l15 & 7);                // k-slice 0 chunk
    const int cx1  = (4 + quad) ^ (l15 & 7);          // k-slice 1 chunk

    f32x4 acc[8][4];
    const f32x4 z = {0.f, 0.f, 0.f, 0.f};
#pragma unroll
    for (int i = 0; i < 8; ++i)
#pragma unroll
        for (int j = 0; j < 4; ++j) acc[i][j] = z;

    const int T = K >> 6;

    auto stage = [&](const unsigned short* Gp, unsigned short* Ls, int kt, int h) {
        const size_t kk = (size_t)kt << 6;
        unsigned short* d = Ls + (kt & 1) * 16384;    // 32 KB buffers
        gl_lds16(Gp + goff[2 * h]     + kk, d + lof[2 * h]);
        gl_lds16(Gp + goff[2 * h + 1] + kk, d + lof[2 * h + 1]);
    };

    // prologue: tile 0 fully staged (8 loads in flight)
    stage(Ab, As0, 0, 0); stage(Ab, As0, 0, 1);
    stage(Bb, Bs0, 0, 0); stage(Bb, Bs0, 0, 1);

    for (int kt = 0; kt < T; ++kt) {
        const unsigned short* aP = As0 + (kt & 1) * 16384;
        const unsigned short* bP = Bs0 + (kt & 1) * 16384;
        const bool pf = (kt + 1 < T);
        short8 bg[4][2];                              // all B frags, read once
#pragma unroll
        for (int ph = 0; ph < 4; ++ph) {
            short8 af[2][2];                          // A m-pair for this phase
            if (ph == 0) {
                if (pf) {
                    stage(Ab, As0, kt + 1, 0);        // 2 loads -> 10 in flight
                    asm volatile("s_waitcnt vmcnt(2)" ::: "memory");  // tile kt done
                } else {
                    asm volatile("s_waitcnt vmcnt(0)" ::: "memory");
                }
                __builtin_amdgcn_s_barrier();         // gate: buf[kt&1] staged
#pragma unroll
                for (int nn = 0; nn < 4; ++nn) {
                    const int ro = (brow + nn * 16) * 8;
                    bg[nn][0] = *(const short8*)(bP + (ro + cx0) * 8);
                    bg[nn][1] = *(const short8*)(bP + (ro + cx1) * 8);
                }
            }
#pragma unroll
            for (int mm = 0; mm < 2; ++mm) {
                const int ro = (arow + (ph * 2 + mm) * 16) * 8;
                af[mm][0] = *(const short8*)(aP + (ro + cx0) * 8);
                af[mm][1] = *(const short8*)(aP + (ro + cx1) * 8);
            }
            if (pf) {
                if (ph == 1)      stage(Ab, As0, kt + 1, 1);
                else if (ph == 2) stage(Bb, Bs0, kt + 1, 0);
                else if (ph == 3) stage(Bb, Bs0, kt + 1, 1);
            }
            if (ph != 0) __builtin_amdgcn_s_barrier();    // align waves pre-MFMA
            asm volatile("s_waitcnt lgkmcnt(0)" ::: "memory");
            __builtin_amdgcn_sched_barrier(0);            // rule #18 fence
            __builtin_amdgcn_s_setprio(1);
#pragma unroll
            for (int mm = 0; mm < 2; ++mm)
#pragma unroll
                for (int nn = 0; nn < 4; ++nn) {
                    const int m = ph * 2 + mm;
                    acc[m][nn] = __builtin_amdgcn_mfma_f32_16x16x32_bf16(
                        af[mm][0], bg[nn][0], acc[m][nn], 0, 0, 0);
                    acc[m][nn] = __builtin_amdgcn_mfma_f32_16x16x32_bf16(
                        af[mm][1], bg[nn][1], acc[m][nn], 0, 0, 0);
                }
            __builtin_amdgcn_s_setprio(0);
            __builtin_amdgcn_s_barrier();                 // reads of buf done
        }
    }

    // C/D layout: col = lane&15, row = quad*4 + reg  [m89/m91 verified]
    unsigned short* CbW = Cb + (size_t)(wm * 128) * N + wn * 64;
#pragma unroll
    for (int i = 0; i < 8; ++i)
#pragma unroll
        for (int j = 0; j < 4; ++j)
#pragma unroll
            for (int r = 0; r < 4; ++r)
                CbW[(size_t)(i * 16 + quad * 4 + r) * N + j * 16 + l15] =
                    f2bf(acc[i][j][r]);

    if (Cm) {   // mirrored tile: r-values contiguous -> coalesced ushort4
        unsigned short* CmW = Cm + (size_t)(wn * 64) * N + wm * 128;
#pragma unroll
        for (int i = 0; i < 8; ++i)
#pragma unroll
            for (int j = 0; j < 4; ++j) {
                ushort4 o;
                o.x = f2bf(acc[i][j][0]);
                o.y = f2bf(acc[i][j][1]);
                o.z = f2bf(acc[i][j][2]);
                o.w = f2bf(acc[i][j][3]);
                *(ushort4*)(CmW + (size_t)(j * 16 + l15) * N + i * 16 + quad * 4) = o;
            }
    }
}

// ---------------------------------------------------------------------------
// Prep: [0,3072)   transpose+cvt x -> xT[b][d][l]
//       [3072,3216) transpose+cvt W -> WT[e][d]
//       [3216,...)  straight cvt main -> mainBF
// ---------------------------------------------------------------------------
__global__ __launch_bounds__(256) void prep_kernel(
    const float* __restrict__ x, unsigned short* __restrict__ xT,
    const float* __restrict__ W, unsigned short* __restrict__ WT,
    const float* __restrict__ mainp, unsigned short* __restrict__ mainBF) {
    const int bid = blockIdx.x;
    const int t   = threadIdx.x;
    if (bid < 3216) {
        __shared__ float tile[64][65];
        const float* src;
        unsigned short* dst;
        int ss, dstride;
        if (bid < 3072) {
            const int lb = bid & 15, rest = bid >> 4;
            const int db = rest % 12, b = rest / 12;
            src = x + ((size_t)b * kLX + lb * 64) * kD + db * 64;
            ss  = kD;
            dst = xT + ((size_t)b * kD + db * 64) * kLX + lb * 64;
            dstride = kLX;
        } else {
            const int ti = bid - 3072;
            const int d0 = (ti / 12) * 64, e0 = (ti % 12) * 64;
            src = W + (size_t)d0 * kD + e0;
            ss  = kD;
            dst = WT + (size_t)e0 * kD + d0;
            dstride = kD;
        }
        const int tx = t & 15, ty = t >> 4;
#pragma unroll
        for (int p = 0; p < 4; ++p) {
            int r = p * 16 + ty;
            float4 v = *(const float4*)(src + (size_t)r * ss + tx * 4);
            *(float4*)&tile[r][tx * 4] = v;
        }
        __syncthreads();
#pragma unroll
        for (int p = 0; p < 4; ++p) {
            int dr = p * 16 + ty;
            ushort4 o;
            o.x = f2bf(tile[tx * 4 + 0][dr]);
            o.y = f2bf(tile[tx * 4 + 1][dr]);
            o.z = f2bf(tile[tx * 4 + 2][dr]);
            o.w = f2bf(tile[tx * 4 + 3][dr]);
            *(ushort4*)(dst + (size_t)dr * dstride + tx * 4) = o;
        }
    } else {
        const long i = (long)(bid - 3216) * 256 + t;     // 8-elem chunk idx
        const long na8 = (long)kB * kLM * kD / 8;
        if (i >= na8) return;
        const float* s = mainp + i * 8;
        writeChunk(mainBF + i * 8, *(const float4*)s, *(const float4*)(s + 4));
    }
}

// ---------------------------------------------------------------------------
// Fused stage 2 (256x256 tiles, 512 thr):
//   [0,96)   G[b] = xT[b] @ xT[b]^T  symmetric: 6 triangle tiles/batch of a
//            3x3 grid, mirror-written
//   [96,288) P[b] = mainBF[b] @ W    (B-operand = WT): 4x3 tiles/batch
// Batch -> XCD pinned in both halves. 288 blocks, 1 block/CU (128 KB LDS).
// ---------------------------------------------------------------------------
__global__ __launch_bounds__(512, 2) void gemm_stage2_kernel(
    const unsigned short* __restrict__ xT,
    const unsigned short* __restrict__ mainBF,
    const unsigned short* __restrict__ WT,
    unsigned short* __restrict__ G, unsigned short* __restrict__ P) {
    __shared__ unsigned short As[2][16384];   // 64 KB
    __shared__ unsigned short Bs[2][16384];   // 64 KB
    const int wgid = blockIdx.x;
    const unsigned short *Ab, *Bb;
    unsigned short *Cb, *Cm = nullptr;
    int K;
    if (wgid < 96) {
        const int xcd = wgid & 7, kk = wgid >> 3;       // kk in [0,12)
        const int grp = kk / 6, til = kk - grp * 6;
        const int b   = grp * 8 + xcd;
        const int bi  = (til >= 3) ? 2 : ((til >= 1) ? 1 : 0);
        const int bj  = til - bi * (bi + 1) / 2;        // bi >= bj
        K = kLX;
        const unsigned short* base = xT + (size_t)b * kD * kLX;
        Ab = base + (size_t)bi * 256 * kLX;
        Bb = base + (size_t)bj * 256 * kLX;
        unsigned short* Gb = G + (size_t)b * kD * kD;
        Cb = Gb + (size_t)bi * 256 * kD + bj * 256;
        if (bi != bj) Cm = Gb + (size_t)bj * 256 * kD + bi * 256;
    } else {
        const int pid = wgid - 96;
        const int xcd = pid & 7, kk = pid >> 3;         // kk in [0,24)
        const int grp = kk / 12, til = kk - grp * 12;
        const int b   = grp * 8 + xcd;
        const int bi  = til & 3, bj = til >> 2;         // 4 x 3 tiles
        K = kD;
        Ab = mainBF + (size_t)b * kLM * kD + (size_t)bi * 256 * kD;
        Bb = WT + (size_t)bj * 256 * kD;
        Cb = P + (size_t)b * kLM * kD + (size_t)bi * 256 * kD + bj * 256;
    }
    gemm_core256(Ab, Bb, Cb, Cm, kD, K, &As[0][0], &Bs[0][0]);
}

// ---------------------------------------------------------------------------
// Stage 3: A[b] = P[b] @ G[b]  (G symmetric -> NT form with B = G directly)
// 192 blocks of 512 thr.
// ---------------------------------------------------------------------------
__global__ __launch_bounds__(512, 2) void gemm_a_kernel(
    const unsigned short* __restrict__ P, const unsigned short* __restrict__ G,
    unsigned short* __restrict__ Ao) {
    __shared__ unsigned short As[2][16384];
    __shared__ unsigned short Bs[2][16384];
    const int wgid = blockIdx.x;
    const int xcd = wgid & 7, kk = wgid >> 3;           // kk in [0,24)
    const int grp = kk / 12, til = kk - grp * 12;
    const int b   = grp * 8 + xcd;
    const int bi  = til & 3, bj = til >> 2;             // 4 x 3 tiles
    const unsigned short* Ab = P + (size_t)b * kLM * kD + (size_t)bi * 256 * kD;
    const unsigned short* Bb = G + (size_t)b * kD * kD + (size_t)bj * 256 * kD;
    unsigned short* Cb = Ao + (size_t)b * kLM * kD + (size_t)bi * 256 * kD + bj * 256;
    gemm_core256(Ab, Bb, Cb, nullptr, kD, kD, &As[0][0], &Bs[0][0]);
}

// ---------------------------------------------------------------------------
// Fused beta + pooled. Grid (64,16). Wave handles 4 rows.
// Cross-wave LDS pre-reduction -> 1 atomicAdd per (s,lane) per block.
// ---------------------------------------------------------------------------
__global__ __launch_bounds__(256) void pool_kernel(
    const float* __restrict__ mainp, const unsigned short* __restrict__ Aout,
    const float* __restrict__ w, float* __restrict__ out) {
    __shared__ float red[4][24][64];   // 24 KB
    const int b     = blockIdx.y;
    const int chunk = blockIdx.x;           // 64 chunks of 16 rows
    const int t     = threadIdx.x;
    const int wave  = t >> 6, lane = t & 63;
    float w1[12], w2[12], ps[12], pm[12];
#pragma unroll
    for (int s = 0; s < 12; ++s) {
        w1[s] = w[s * 64 + lane];
        w2[s] = w[kD + s * 64 + lane];
        ps[s] = 0.f; pm[s] = 0.f;
    }
#pragma unroll
    for (int rr = 0; rr < 4; ++rr) {
        const int row = chunk * 16 + rr * 4 + wave;
        const float* mr = mainp + ((size_t)b * kLM + row) * kD;
        const unsigned short* ar = Aout + ((size_t)b * kLM + row) * kD;
        float sv[12], mv[12], acc = 0.f;
#pragma unroll
        for (int s = 0; s < 12; ++s) {
            float m_ = mr[s * 64 + lane];
            float a_ = bf2f(ar[s * 64 + lane]);
            sv[s] = m_ - a_;
            mv[s] = m_ * a_;
            acc += sv[s] * w1[s] + mv[s] * w2[s];
        }
#pragma unroll
        for (int off = 32; off; off >>= 1) acc += __shfl_xor(acc, off);
#pragma unroll
        for (int s = 0; s < 12; ++s) { ps[s] += acc * sv[s]; pm[s] += acc * mv[s]; }
    }
#pragma unroll
    for (int s = 0; s < 12; ++s) {
        red[wave][s][lane]      = ps[s];
        red[wave][12 + s][lane] = pm[s];
    }
    __syncthreads();
    float* ob = out + (size_t)b * 2 * kD;
    for (int v = t; v < 24 * 64; v += 256) {
        const int sl = v >> 6, ln = v & 63;
        const float sum = red[0][sl][ln] + red[1][sl][ln] +
                          red[2][sl][ln] + red[3][sl][ln];
        const int d = (sl < 12) ? sl * 64 + ln : kD + (sl - 12) * 64 + ln;
        atomicAdd(&ob[d], sum);
    }
}

extern "C" void kernel_launch(void* const* d_in, const int* in_sizes, int n_in,
                              void* d_out, int out_size, void* d_ws, size_t ws_size,
                              hipStream_t stream) {
    const float* mainp = (const float*)d_in[0];  // (B, LM, D)
    const float* x     = (const float*)d_in[1];  // (B, LX, D)
    const float* W     = (const float*)d_in[2];  // (D, D)
    const float* w     = (const float*)d_in[3];  // (2D, 1)
    float* out = (float*)d_out;                  // (B, 2D)

    char* p = (char*)d_ws;
    unsigned short* xT     = (unsigned short*)p; p += (size_t)kB * kD * kLX * 2;
    unsigned short* G      = (unsigned short*)p; p += (size_t)kB * kD * kD * 2;
    unsigned short* P      = (unsigned short*)p; p += (size_t)kB * kLM * kD * 2;
    unsigned short* Ao     = (unsigned short*)p; p += (size_t)kB * kLM * kD * 2;
    unsigned short* WT     = (unsigned short*)p; p += (size_t)kD * kD * 2;
    unsigned short* mainBF = (unsigned short*)p; p += (size_t)kB * kLM * kD * 2;

    hipMemsetAsync(out, 0, (size_t)kB * 2 * kD * sizeof(float), stream);

    // x -> xT (transposed bf16), W -> WT (transposed bf16), main -> bf16
    prep_kernel<<<dim3(3216 + kB * kLM * kD / 8 / 256), 256, 0, stream>>>(
        x, xT, W, WT, mainp, mainBF);

    // G = xT xT^T (triangle+mirror)  ||  P = main @ W   (independent, fused)
    gemm_stage2_kernel<<<dim3(288), 512, 0, stream>>>(xT, mainBF, WT, G, P);

    // A = P @ G  (G symmetric)
    gemm_a_kernel<<<dim3(192), 512, 0, stream>>>(P, G, Ao);

    pool_kernel<<<dim3(kLM / 16, kB), 256, 0, stream>>>(mainp, Ao, w, out);
}